// Round 5
// baseline (137.927 us; speedup 1.0000x reference)
//
#include <hip/hip_runtime.h>

// Problem constants (fixed by setup_inputs): B=4096, D=512, H=W=64, N=4096.
#define B_ROWS 4096
#define N_COLS 4096
#define DIM    512
#define LDK    1024   // row stride (elements) of split bf16 arrays [hi(512) | lo(512)]

typedef __attribute__((ext_vector_type(8))) short short8;
typedef __attribute__((ext_vector_type(4))) float floatx4;

// bf16 round-to-nearest-even split helpers (bit-exact, no API dependence)
__device__ __forceinline__ unsigned short f2bf_rn(float f) {
    unsigned u = __float_as_uint(f);
    u += 0x7fffu + ((u >> 16) & 1u);
    return (unsigned short)(u >> 16);
}
__device__ __forceinline__ float bf2f(unsigned short h) {
    return __uint_as_float(((unsigned)h) << 16);
}

// Monotone float->uint map; (key<<32)|idx gives u64 atomicMin argmin with
// smallest-index tie-break (matches numpy argmin semantics).
__device__ __forceinline__ unsigned long long pack_key(float v, int idx) {
    unsigned u = __float_as_uint(v);
    u = (u & 0x80000000u) ? ~u : (u | 0x80000000u);
    return ((unsigned long long)u << 32) | (unsigned)idx;
}

// Async global->LDS, 16B per lane. LDS dest is wave-uniform base + lane*16;
// global source address IS per-lane (m173) -> we stage fragment-order.
__device__ __forceinline__ void async16(const unsigned short* g, unsigned short* l) {
    __builtin_amdgcn_global_load_lds(
        (__attribute__((address_space(1))) void*)g,
        (__attribute__((address_space(3))) void*)l, 16, 0, 0);
}

// One wave per row (4 rows/block): split fp32 row into bf16 hi/lo halves,
// compute exact fp32 ||row||^2, init packed argmin accumulators. (unchanged)
__global__ __launch_bounds__(256) void som_convert(
    const float* __restrict__ X, const float* __restrict__ Wt,
    unsigned short* __restrict__ Xc, unsigned short* __restrict__ Wc,
    float* __restrict__ x_sq, float* __restrict__ w_sq,
    unsigned long long* __restrict__ packed)
{
    int wave = threadIdx.x >> 6, lane = threadIdx.x & 63;
    int grow = blockIdx.x * 4 + wave;            // 0..8191
    bool isX = grow < B_ROWS;
    const float* src = isX ? (X + (size_t)grow * DIM)
                           : (Wt + (size_t)(grow - B_ROWS) * DIM);
    const float4* p4 = (const float4*)src;
    float4 a = p4[lane * 2], b = p4[lane * 2 + 1];
    float f[8] = {a.x, a.y, a.z, a.w, b.x, b.y, b.z, b.w};
    short8 hi, lo;
    float s = 0.f;
    #pragma unroll
    for (int t = 0; t < 8; ++t) {
        unsigned short h = f2bf_rn(f[t]);
        hi[t] = (short)h;
        lo[t] = (short)f2bf_rn(f[t] - bf2f(h));
        s = fmaf(f[t], f[t], s);
    }
    unsigned short* dst = (isX ? Xc + (size_t)grow * LDK
                               : Wc + (size_t)(grow - B_ROWS) * LDK) + lane * 8;
    *(short8*)(dst)       = hi;
    *(short8*)(dst + 512) = lo;
    #pragma unroll
    for (int off = 32; off >= 1; off >>= 1) s += __shfl_xor(s, off, 64);
    if (lane == 0) {
        if (isX) { x_sq[grow] = s; packed[grow] = ~0ull; }
        else     { w_sq[grow - B_ROWS] = s; }
    }
}

// ---------------------------------------------------------------------------
// Split-bf16 distance GEMM v6 = v1's structure (128x128 tile, 4 waves 2x2,
// BK=32, single 32KB LDS buffer, 2 __syncthreads per K-step, merged 3-product
// clusters, ~2.6-3 blocks/CU for cross-block latency hiding) with v1's two
// measured inefficiencies fixed:
//  (1) fragment-order 1KB subtile LDS layout (staging writes AND ds_read_b128
//      fragment reads are lane-linear 16B) -> bank conflicts 4.19M -> ~0
//  (2) bijective XCD-aware grid swizzle (16x8 rectangle per XCD) -> L2
//      locality, FETCH 37MB -> ~26MB (proven in v4/v5)
// LDS map (shorts): A_hi sub r: r*512 | A_lo: 4096+r*512 | B_hi: 8192+r*512
// | B_lo: 12288+r*512, r=0..7 (16 rows x 32 k per subtile, fragment order:
// word l = row (l&15), k-elems (l>>4)*8..+8).
// Per-acc product order identical to v1 (hh, ah*bl, al*bh; k ascending)
// => bit-exact.
// ---------------------------------------------------------------------------
__global__ __launch_bounds__(256, 3) void som_dist_v6(
    const unsigned short* __restrict__ Xc, const unsigned short* __restrict__ Wc,
    const float* __restrict__ w_sq, unsigned long long* __restrict__ packed)
{
    __shared__ __align__(16) unsigned short L[16384];   // 32 KiB
    const int tid  = threadIdx.x;
    const int wave = tid >> 6, lane = tid & 63;
    const int quad = lane >> 4, t16 = lane & 15;
    const int wr = wave >> 1, wc = wave & 1;       // 2x2 wave grid (64x64 out/wave)

    // XCD-aware bijective swizzle: 1024 blocks -> 8 XCDs x (16x8 rectangle).
    // Consecutive same-XCD dispatches walk bm fast (B panel stays L2-hot).
    const int bid = blockIdx.y * 32 + blockIdx.x;  // 0..1023
    const int xcd = bid & 7, wix = bid >> 3;       // wix 0..127
    const int bm = (xcd >> 2) * 16 + (wix & 15);   // 0..31
    const int bn = (xcd & 3) * 8 + (wix >> 4);     // 0..31

    // Staging: waves 0-1 stage A rows [sg*64, sg*64+64), waves 2-3 stage B.
    // 8 async16/wave/K-step: 4 subtile-hi + 4 subtile-lo, fragment order.
    const int sg = wave & 1;
    const bool stB = (wave >= 2);
    const unsigned short* gsrc =
        (stB ? Wc + (size_t)bn * 128 * LDK : Xc + (size_t)bm * 128 * LDK)
        + (size_t)(sg * 64 + t16) * LDK + quad * 8;
    unsigned short* const lhi = &L[(stB ? 8192 : 0) + sg * 2048];  // subs sg*4..+3
    unsigned short* const llo = lhi + 4096;

    // Fragment read bases (subtile-linear: lane*16B => conflict-free)
    const unsigned short* const pA = &L[wr * 2048 + lane * 8];         // ah i: +i*512; al: +4096
    const unsigned short* const pB = &L[8192 + wc * 2048 + lane * 8];  // bh j: +j*512; bl: +4096

    floatx4 acc[4][4];
    #pragma unroll
    for (int i = 0; i < 4; ++i)
        #pragma unroll
        for (int j = 0; j < 4; ++j) acc[i][j] = (floatx4){0.f, 0.f, 0.f, 0.f};

    #pragma unroll 1
    for (int k0 = 0; k0 < DIM; k0 += 32) {
        __syncthreads();                       // prev tile fully consumed
        #pragma unroll
        for (int q = 0; q < 4; ++q) {
            async16(gsrc + k0 + q * 16 * LDK,       lhi + q * 512);
            async16(gsrc + k0 + q * 16 * LDK + 512, llo + q * 512);
        }
        __syncthreads();                       // staged data visible (vmcnt(0) drain)

        short8 ah[4], bh[4], x[4];
        #pragma unroll
        for (int i = 0; i < 4; ++i) ah[i] = *(const short8*)(pA + i * 512);
        #pragma unroll
        for (int j = 0; j < 4; ++j) bh[j] = *(const short8*)(pB + j * 512);
        #pragma unroll
        for (int i = 0; i < 4; ++i)
            #pragma unroll
            for (int j = 0; j < 4; ++j)
                acc[i][j] = __builtin_amdgcn_mfma_f32_16x16x32_bf16(
                    ah[i], bh[j], acc[i][j], 0, 0, 0);

        #pragma unroll
        for (int j = 0; j < 4; ++j) x[j] = *(const short8*)(pB + j * 512 + 4096);
        #pragma unroll
        for (int i = 0; i < 4; ++i)
            #pragma unroll
            for (int j = 0; j < 4; ++j)
                acc[i][j] = __builtin_amdgcn_mfma_f32_16x16x32_bf16(
                    ah[i], x[j], acc[i][j], 0, 0, 0);

        #pragma unroll
        for (int i = 0; i < 4; ++i) x[i] = *(const short8*)(pA + i * 512 + 4096);
        #pragma unroll
        for (int i = 0; i < 4; ++i)
            #pragma unroll
            for (int j = 0; j < 4; ++j)
                acc[i][j] = __builtin_amdgcn_mfma_f32_16x16x32_bf16(
                    x[i], bh[j], acc[i][j], 0, 0, 0);
    }

    // Epilogue: val = w_sq - 2*dot (x_sq is per-row constant, irrelevant to
    // argmin). C/D layout: col = t16, row = quad*4 + reg  [m89/m91].
    const int col0 = bn * 128 + wc * 64 + t16;
    float wq[4];
    #pragma unroll
    for (int j = 0; j < 4; ++j) wq[j] = w_sq[col0 + j * 16];
    const int row_base = bm * 128 + wr * 64 + quad * 4;
    #pragma unroll
    for (int i = 0; i < 4; ++i) {
        #pragma unroll
        for (int r = 0; r < 4; ++r) {
            unsigned long long best = ~0ull;
            #pragma unroll
            for (int j = 0; j < 4; ++j) {
                float val = fmaf(-2.f, acc[i][j][r], wq[j]);
                unsigned long long key = pack_key(val, col0 + j * 16);
                best = (key < best) ? key : best;
            }
            #pragma unroll
            for (int m = 1; m <= 8; m <<= 1) {     // reduce 16-lane col group
                unsigned long long o = __shfl_xor(best, m, 64);
                best = (o < best) ? o : best;
            }
            if (t16 == 0)
                atomicMin(&packed[row_base + i * 16 + r], best);
        }
    }
}

// Unpack argmin, qe = sqrt(max(||x||^2 + val, 0)).
// d_out: bmu_indices (4096 x 2) flat, then qe (4096), all float. (unchanged)
__global__ __launch_bounds__(256) void som_finalize(
    const unsigned long long* __restrict__ packed,
    const float* __restrict__ x_sq, float* __restrict__ out)
{
    int b = blockIdx.x * 256 + threadIdx.x;  // 0..4095
    unsigned long long p = packed[b];
    unsigned idx = (unsigned)(p & 0xffffffffull);
    unsigned key = (unsigned)(p >> 32);
    unsigned u = (key & 0x80000000u) ? (key & 0x7fffffffu) : ~key;
    float val = __uint_as_float(u);
    float sq = fmaxf(x_sq[b] + val, 0.f);
    out[2 * b]     = (float)(idx >> 6);   // y = idx / 64
    out[2 * b + 1] = (float)(idx & 63);   // x = idx % 64
    out[2 * B_ROWS + b] = sqrtf(sq);
}

extern "C" void kernel_launch(void* const* d_in, const int* in_sizes, int n_in,
                              void* d_out, int out_size, void* d_ws, size_t ws_size,
                              hipStream_t stream) {
    const float* X  = (const float*)d_in[0];   // (4096, 512)
    const float* Wt = (const float*)d_in[1];   // (64, 64, 512) -> (4096, 512)
    float* out = (float*)d_out;

    // ws layout: [0,32K) packed u64[4096]; [32K,48K) x_sq; [48K,64K) w_sq;
    // [64K, 64K+8M) Xc bf16 split; [64K+8M, 64K+16M) Wc bf16 split.
    unsigned long long* packed = (unsigned long long*)d_ws;
    float* x_sq = (float*)((char*)d_ws + (32 << 10));
    float* w_sq = (float*)((char*)d_ws + (48 << 10));
    unsigned short* Xc = (unsigned short*)((char*)d_ws + (64 << 10));
    unsigned short* Wc = (unsigned short*)((char*)d_ws + (64 << 10) + ((size_t)B_ROWS * LDK * 2));

    som_convert<<<dim3((B_ROWS + N_COLS) / 4), dim3(256), 0, stream>>>(
        X, Wt, Xc, Wc, x_sq, w_sq, packed);
    som_dist_v6<<<dim3(32, 32), dim3(256), 0, stream>>>(
        Xc, Wc, w_sq, packed);
    som_finalize<<<dim3(B_ROWS / 256), dim3(256), 0, stream>>>(packed, x_sq, out);
}

// Round 6
// 123.960 us; speedup vs baseline: 1.1127x; 1.1127x over previous
//
#include <hip/hip_runtime.h>

// Problem constants (fixed by setup_inputs): B=4096, D=512, H=W=64, N=4096.
#define B_ROWS 4096
#define N_COLS 4096
#define DIM    512
#define LDK    1024   // row stride (elements) of split bf16 arrays [hi(512) | lo(512)]

typedef __attribute__((ext_vector_type(8))) short short8;
typedef __attribute__((ext_vector_type(4))) float floatx4;

// bf16 round-to-nearest-even split helpers (bit-exact, no API dependence)
__device__ __forceinline__ unsigned short f2bf_rn(float f) {
    unsigned u = __float_as_uint(f);
    u += 0x7fffu + ((u >> 16) & 1u);
    return (unsigned short)(u >> 16);
}
__device__ __forceinline__ float bf2f(unsigned short h) {
    return __uint_as_float(((unsigned)h) << 16);
}

// Monotone float->uint map; (key<<32)|idx gives u64 atomicMin argmin with
// smallest-index tie-break (matches numpy argmin semantics).
__device__ __forceinline__ unsigned long long pack_key(float v, int idx) {
    unsigned u = __float_as_uint(v);
    u = (u & 0x80000000u) ? ~u : (u | 0x80000000u);
    return ((unsigned long long)u << 32) | (unsigned)idx;
}

// Async global->LDS, 16B per lane. LDS dest is wave-uniform base + lane*16;
// global source address IS per-lane (m173).
__device__ __forceinline__ void async16(const unsigned short* g, unsigned short* l) {
    __builtin_amdgcn_global_load_lds(
        (__attribute__((address_space(1))) void*)g,
        (__attribute__((address_space(3))) void*)l, 16, 0, 0);
}

// One wave per row (4 rows/block): split fp32 row into bf16 hi/lo halves,
// compute exact fp32 ||row||^2, init packed argmin accumulators. (unchanged)
__global__ __launch_bounds__(256) void som_convert(
    const float* __restrict__ X, const float* __restrict__ Wt,
    unsigned short* __restrict__ Xc, unsigned short* __restrict__ Wc,
    float* __restrict__ x_sq, float* __restrict__ w_sq,
    unsigned long long* __restrict__ packed)
{
    int wave = threadIdx.x >> 6, lane = threadIdx.x & 63;
    int grow = blockIdx.x * 4 + wave;            // 0..8191
    bool isX = grow < B_ROWS;
    const float* src = isX ? (X + (size_t)grow * DIM)
                           : (Wt + (size_t)(grow - B_ROWS) * DIM);
    const float4* p4 = (const float4*)src;
    float4 a = p4[lane * 2], b = p4[lane * 2 + 1];
    float f[8] = {a.x, a.y, a.z, a.w, b.x, b.y, b.z, b.w};
    short8 hi, lo;
    float s = 0.f;
    #pragma unroll
    for (int t = 0; t < 8; ++t) {
        unsigned short h = f2bf_rn(f[t]);
        hi[t] = (short)h;
        lo[t] = (short)f2bf_rn(f[t] - bf2f(h));
        s = fmaf(f[t], f[t], s);
    }
    unsigned short* dst = (isX ? Xc + (size_t)grow * LDK
                               : Wc + (size_t)(grow - B_ROWS) * LDK) + lane * 8;
    *(short8*)(dst)       = hi;
    *(short8*)(dst + 512) = lo;
    #pragma unroll
    for (int off = 32; off >= 1; off >>= 1) s += __shfl_xor(s, off, 64);
    if (lane == 0) {
        if (isX) { x_sq[grow] = s; packed[grow] = ~0ull; }
        else     { w_sq[grow - B_ROWS] = s; }
    }
}

// ---------------------------------------------------------------------------
// Split-bf16 distance GEMM v7 = v1's exact structure (128x128 tile, 4 waves
// 2x2, BK=32, single 32KB LDS, 2 __syncthreads/K-step, merged 3-product
// clusters, 3 blocks/CU for cross-block latency hiding, default block
// mapping) + granule-rotation LDS swizzle:
//   subtile = 16 rows x 32 elems (1KB) as 64 granules of 16B;
//   granule (r,g) stored at word w = 4r + ((g + ((r>>1)&3)) & 3).
// Staging (lane l writes word l): global row l>>2, chunk ((l&3)-((l>>3)&3))&3
//   -> 4 consecutive lanes read 4 distinct chunks of ONE row = one 64B
//   segment per 4 lanes: IDENTICAL coalescing to v1 (v6's regression was the
//   16B-scatter staging pattern, 4x VMEM requests).
// Fragment read (lane l needs row l&15, chunk l>>4): word
//   4*t16 + ((quad + ((t16>>1)&3))&3); per quarter-wave w mod 8 covers each
//   4-bank group exactly twice -> 2-way conflict = free [m136] (v1 was 8-way,
//   4.19M conflict cycles).
// Same granule per lane fragment as v1 -> bit-exact.
// ---------------------------------------------------------------------------
__global__ __launch_bounds__(256, 3) void som_dist_v7(
    const unsigned short* __restrict__ Xc, const unsigned short* __restrict__ Wc,
    const float* __restrict__ w_sq, unsigned long long* __restrict__ packed)
{
    __shared__ __align__(16) unsigned short Ah[128 * 32];   // 8 subtiles x 1KB
    __shared__ __align__(16) unsigned short Al[128 * 32];
    __shared__ __align__(16) unsigned short Bh[128 * 32];
    __shared__ __align__(16) unsigned short Bl[128 * 32];
    const int tid  = threadIdx.x;
    const int wave = tid >> 6, lane = tid & 63;
    const int wr = wave >> 1, wc = wave & 1;       // 2x2 wave grid
    const int bm = blockIdx.y, bn = blockIdx.x;
    const int quad = lane >> 4, t16 = lane & 15;

    // Staging: wave stages rows [wave*32, wave*32+32) of all four tiles,
    // 8 async16/iter (2 subtiles per array). Rotated chunk keeps 64B-segment
    // coalescing while matching the swizzled LDS image.
    const int srow = lane >> 2;                            // 0..15
    const int scol = ((((lane & 3) - ((lane >> 3) & 3)) & 3)) * 8;  // rotated 16B chunk
    const unsigned short* gAh = Xc + (size_t)(bm * 128 + wave * 32 + srow) * LDK + scol;
    const unsigned short* gBh = Wc + (size_t)(bn * 128 + wave * 32 + srow) * LDK + scol;
    const unsigned short* gAl = gAh + 512;
    const unsigned short* gBl = gBh + 512;
    unsigned short* lAh = &Ah[(wave * 32) * 32];
    unsigned short* lAl = &Al[(wave * 32) * 32];
    unsigned short* lBh = &Bh[(wave * 32) * 32];
    unsigned short* lBl = &Bl[(wave * 32) * 32];

    // Fragment read offset: word within subtile for (row t16, chunk quad)
    // under the rotation; fragment i lives at subtile (wr*4 + i) => +i*512.
    const int rdw = 4 * t16 + ((quad + ((t16 >> 1) & 3)) & 3);
    const unsigned short* pah = &Ah[wr * 2048 + rdw * 8];
    const unsigned short* pal = &Al[wr * 2048 + rdw * 8];
    const unsigned short* pbh = &Bh[wc * 2048 + rdw * 8];
    const unsigned short* pbl = &Bl[wc * 2048 + rdw * 8];

    floatx4 acc[4][4];
    #pragma unroll
    for (int i = 0; i < 4; ++i)
        #pragma unroll
        for (int j = 0; j < 4; ++j) acc[i][j] = (floatx4){0.f, 0.f, 0.f, 0.f};

    #pragma unroll 1
    for (int k0 = 0; k0 < DIM; k0 += 32) {
        __syncthreads();                       // prev tile fully consumed
        async16(gAh + k0,            lAh);
        async16(gAh + k0 + 16 * LDK, lAh + 512);
        async16(gAl + k0,            lAl);
        async16(gAl + k0 + 16 * LDK, lAl + 512);
        async16(gBh + k0,            lBh);
        async16(gBh + k0 + 16 * LDK, lBh + 512);
        async16(gBl + k0,            lBl);
        async16(gBl + k0 + 16 * LDK, lBl + 512);
        __syncthreads();                       // staged data visible

        short8 ah[4], bh[4], x[4];
        #pragma unroll
        for (int i = 0; i < 4; ++i) ah[i] = *(const short8*)(pah + i * 512);
        #pragma unroll
        for (int j = 0; j < 4; ++j) bh[j] = *(const short8*)(pbh + j * 512);
        #pragma unroll
        for (int i = 0; i < 4; ++i)
            #pragma unroll
            for (int j = 0; j < 4; ++j)
                acc[i][j] = __builtin_amdgcn_mfma_f32_16x16x32_bf16(
                    ah[i], bh[j], acc[i][j], 0, 0, 0);

        #pragma unroll
        for (int j = 0; j < 4; ++j) x[j] = *(const short8*)(pbl + j * 512);
        #pragma unroll
        for (int i = 0; i < 4; ++i)
            #pragma unroll
            for (int j = 0; j < 4; ++j)
                acc[i][j] = __builtin_amdgcn_mfma_f32_16x16x32_bf16(
                    ah[i], x[j], acc[i][j], 0, 0, 0);

        #pragma unroll
        for (int i = 0; i < 4; ++i) x[i] = *(const short8*)(pal + i * 512);
        #pragma unroll
        for (int i = 0; i < 4; ++i)
            #pragma unroll
            for (int j = 0; j < 4; ++j)
                acc[i][j] = __builtin_amdgcn_mfma_f32_16x16x32_bf16(
                    x[i], bh[j], acc[i][j], 0, 0, 0);
    }

    // Epilogue: val = w_sq - 2*dot (x_sq is per-row constant, irrelevant to
    // argmin). C/D layout: col = t16, row = quad*4 + reg  [m89/m91].
    const int col0 = bn * 128 + wc * 64 + t16;
    float wq[4];
    #pragma unroll
    for (int j = 0; j < 4; ++j) wq[j] = w_sq[col0 + j * 16];
    const int row_base = bm * 128 + wr * 64 + quad * 4;
    #pragma unroll
    for (int i = 0; i < 4; ++i) {
        #pragma unroll
        for (int r = 0; r < 4; ++r) {
            unsigned long long best = ~0ull;
            #pragma unroll
            for (int j = 0; j < 4; ++j) {
                float val = fmaf(-2.f, acc[i][j][r], wq[j]);
                unsigned long long key = pack_key(val, col0 + j * 16);
                best = (key < best) ? key : best;
            }
            #pragma unroll
            for (int m = 1; m <= 8; m <<= 1) {     // reduce 16-lane col group
                unsigned long long o = __shfl_xor(best, m, 64);
                best = (o < best) ? o : best;
            }
            if (t16 == 0)
                atomicMin(&packed[row_base + i * 16 + r], best);
        }
    }
}

// Unpack argmin, qe = sqrt(max(||x||^2 + val, 0)).
// d_out: bmu_indices (4096 x 2) flat, then qe (4096), all float. (unchanged)
__global__ __launch_bounds__(256) void som_finalize(
    const unsigned long long* __restrict__ packed,
    const float* __restrict__ x_sq, float* __restrict__ out)
{
    int b = blockIdx.x * 256 + threadIdx.x;  // 0..4095
    unsigned long long p = packed[b];
    unsigned idx = (unsigned)(p & 0xffffffffull);
    unsigned key = (unsigned)(p >> 32);
    unsigned u = (key & 0x80000000u) ? (key & 0x7fffffffu) : ~key;
    float val = __uint_as_float(u);
    float sq = fmaxf(x_sq[b] + val, 0.f);
    out[2 * b]     = (float)(idx >> 6);   // y = idx / 64
    out[2 * b + 1] = (float)(idx & 63);   // x = idx % 64
    out[2 * B_ROWS + b] = sqrtf(sq);
}

extern "C" void kernel_launch(void* const* d_in, const int* in_sizes, int n_in,
                              void* d_out, int out_size, void* d_ws, size_t ws_size,
                              hipStream_t stream) {
    const float* X  = (const float*)d_in[0];   // (4096, 512)
    const float* Wt = (const float*)d_in[1];   // (64, 64, 512) -> (4096, 512)
    float* out = (float*)d_out;

    // ws layout: [0,32K) packed u64[4096]; [32K,48K) x_sq; [48K,64K) w_sq;
    // [64K, 64K+8M) Xc bf16 split; [64K+8M, 64K+16M) Wc bf16 split.
    unsigned long long* packed = (unsigned long long*)d_ws;
    float* x_sq = (float*)((char*)d_ws + (32 << 10));
    float* w_sq = (float*)((char*)d_ws + (48 << 10));
    unsigned short* Xc = (unsigned short*)((char*)d_ws + (64 << 10));
    unsigned short* Wc = (unsigned short*)((char*)d_ws + (64 << 10) + ((size_t)B_ROWS * LDK * 2));

    som_convert<<<dim3((B_ROWS + N_COLS) / 4), dim3(256), 0, stream>>>(
        X, Wt, Xc, Wc, x_sq, w_sq, packed);
    som_dist_v7<<<dim3(N_COLS / 128, B_ROWS / 128), dim3(256), 0, stream>>>(
        Xc, Wc, w_sq, packed);
    som_finalize<<<dim3(B_ROWS / 256), dim3(256), 0, stream>>>(packed, x_sq, out);
}